// Round 3
// baseline (237.180 us; speedup 1.0000x reference)
//
#include <hip/hip_runtime.h>
#include <math.h>

// Problem constants (match reference)
#define B_N 8
#define A_N 49104
#define M_N 50
#define K_N 80
#define BETA_C (1.0f / 9.0f)

#define NB1 192                  // ceil(A_N/256) blocks per image for assign
#define NQ  (A_N * K_N / 4)      // 982080 float4 elements per image
#define NC2 3837                 // ceil(NQ/256) blocks per image for focal

__device__ __forceinline__ float wred(float v) {
#pragma unroll
    for (int off = 32; off > 0; off >>= 1) v += __shfl_down(v, off, 64);
    return v;
}

// Kernel 1: per-anchor box assignment + regression loss partials.
// grid = (NB1, B_N), block = 256
__global__ __launch_bounds__(256) void assign_kernel(
    const float* __restrict__ anchors,   // (A,4)
    const float* __restrict__ reg,       // (B,A,4)
    const float* __restrict__ boxes,     // (B,M,4), -1 padded
    const int* __restrict__ classes,     // (B,M)
    int* __restrict__ status,            // (B,A): -1 ignore, 0 neg, c>=1 pos class
    float* __restrict__ regpart,         // (B,NB1)
    float* __restrict__ npospart)        // (B,NB1)
{
    const int b = blockIdx.y;
    const int a = blockIdx.x * 256 + threadIdx.x;

    __shared__ float sb[M_N * 4];
    __shared__ int   sc[M_N];
    if (threadIdx.x < M_N * 4) sb[threadIdx.x] = boxes[b * M_N * 4 + threadIdx.x];
    if (threadIdx.x < M_N)     sc[threadIdx.x] = classes[b * M_N + threadIdx.x];
    __syncthreads();

    float regl = 0.0f;
    float posf = 0.0f;

    if (a < A_N) {
        const float4 an = ((const float4*)anchors)[a];
        const float aw = an.z - an.x;
        const float ah = an.w - an.y;
        const float areaA = aw * ah;

        float best = -2.0f;
        int bi = 0;
#pragma unroll 5
        for (int m = 0; m < M_N; ++m) {
            const float bx0 = sb[4 * m + 0];
            const float by0 = sb[4 * m + 1];
            const float bx1 = sb[4 * m + 2];
            const float by1 = sb[4 * m + 3];
            float val = -1.0f;           // masked (invalid) boxes -> -1.0 exactly
            if (bx0 != -1.0f) {
                const float iw = fmaxf(fminf(an.z, bx1) - fmaxf(an.x, bx0), 0.0f);
                const float ih = fmaxf(fminf(an.w, by1) - fmaxf(an.y, by0), 0.0f);
                const float inter = iw * ih;
                const float ua = fmaxf(areaA + (bx1 - bx0) * (by1 - by0) - inter, 1e-8f);
                val = inter / ua;
            }
            if (val > best) { best = val; bi = m; }  // strict > == first argmax
        }

        int s;
        if (best >= 0.5f) {
            s = sc[bi];
            posf = 1.0f;
            // regression loss for positive anchor
            const float4 r = ((const float4*)reg)[b * A_N + a];
            const float gx0 = sb[4 * bi + 0], gy0 = sb[4 * bi + 1];
            const float gx1 = sb[4 * bi + 2], gy1 = sb[4 * bi + 3];
            const float acx = an.x + 0.5f * aw;
            const float acy = an.y + 0.5f * ah;
            const float gw0 = gx1 - gx0;
            const float gh0 = gy1 - gy0;
            const float gcx = gx0 + 0.5f * gw0;
            const float gcy = gy0 + 0.5f * gh0;
            const float gw = fmaxf(gw0, 1.0f);
            const float gh = fmaxf(gh0, 1.0f);
            const float t0 = ((gcx - acx) / aw) / 0.1f;
            const float t1 = ((gcy - acy) / ah) / 0.1f;
            const float t2 = logf(gw / aw) / 0.2f;
            const float t3 = logf(gh / ah) / 0.2f;
            float d, sl;
            d = fabsf(t0 - r.x); sl  = (d <= BETA_C) ? 0.5f * d * d / BETA_C : d - 0.5f * BETA_C;
            d = fabsf(t1 - r.y); sl += (d <= BETA_C) ? 0.5f * d * d / BETA_C : d - 0.5f * BETA_C;
            d = fabsf(t2 - r.z); sl += (d <= BETA_C) ? 0.5f * d * d / BETA_C : d - 0.5f * BETA_C;
            d = fabsf(t3 - r.w); sl += (d <= BETA_C) ? 0.5f * d * d / BETA_C : d - 0.5f * BETA_C;
            regl = sl;
        } else {
            s = (best < 0.4f) ? 0 : -1;
        }
        status[b * A_N + a] = s;
    }

    // block reduce (regl, posf)
    const float rw = wred(regl);
    const float pw = wred(posf);
    __shared__ float sred[8];
    const int lane = threadIdx.x & 63, wid = threadIdx.x >> 6;
    if (lane == 0) { sred[wid] = rw; sred[4 + wid] = pw; }
    __syncthreads();
    if (threadIdx.x == 0) {
        regpart[b * NB1 + blockIdx.x]  = sred[0] + sred[1] + sred[2] + sred[3];
        npospart[b * NB1 + blockIdx.x] = sred[4] + sred[5] + sred[6] + sred[7];
    }
}

// Kernel 2: focal loss over all (a,k) elements. One float4 per thread.
// Only delta vs R1: the logits load is skipped entirely for ignored anchors
// (status < 0) — changes bytes fetched, never any computed value.
// grid = (NC2, B_N), block = 256
__global__ __launch_bounds__(256) void focal_kernel(
    const float* __restrict__ logits,    // (B, A*K)
    const int* __restrict__ status,      // (B, A)
    float* __restrict__ clspart)         // (B, NC2)
{
    const int b = blockIdx.y;
    const int i4 = blockIdx.x * 256 + threadIdx.x;

    float sum = 0.0f;
    if (i4 < NQ) {
        const int e = i4 * 4;            // element index within image
        const int a = e / K_N;           // K=80, float4 never crosses a row
        const int k0 = e - a * K_N;
        const int s = status[b * A_N + a];
        if (s >= 0) {                    // not ignored: load + accumulate
            const float4 p4 = ((const float4*)(logits + (size_t)b * (A_N * (size_t)K_N)))[i4];
            const float pv[4] = {p4.x, p4.y, p4.z, p4.w};
#pragma unroll
            for (int j = 0; j < 4; ++j) {
                float p = fminf(fmaxf(pv[j], 1e-4f), 1.0f - 1e-4f);
                const bool ispos = (s >= 1) && (k0 + j == s - 1);
                // pos: 0.25*(1-p)^2*(-log p); neg: 0.75*p^2*(-log(1-p))
                const float la = ispos ? p : (1.0f - p);   // log argument
                const float fw = 1.0f - la;                 // focal weight
                const float alpha = ispos ? 0.25f : 0.75f;
                sum += alpha * fw * fw * (-logf(la));
            }
        }
    }

    const float w = wred(sum);
    __shared__ float sred[4];
    const int lane = threadIdx.x & 63, wid = threadIdx.x >> 6;
    if (lane == 0) sred[wid] = w;
    __syncthreads();
    if (threadIdx.x == 0)
        clspart[b * NC2 + blockIdx.x] = sred[0] + sred[1] + sred[2] + sred[3];
}

// Kernel 3: final reduction + normalization. 1 block, 256 threads.
__global__ __launch_bounds__(256) void finalize_kernel(
    const float* __restrict__ clspart,
    const float* __restrict__ regpart,
    const float* __restrict__ npospart,
    float* __restrict__ out)
{
    __shared__ float sred[12];
    float clsAcc = 0.0f, regAcc = 0.0f;  // meaningful on thread 0 only

    for (int b = 0; b < B_N; ++b) {
        float cs = 0.0f, rs = 0.0f, np = 0.0f;
        for (int i = threadIdx.x; i < NC2; i += 256) cs += clspart[b * NC2 + i];
        for (int i = threadIdx.x; i < NB1; i += 256) {
            rs += regpart[b * NB1 + i];
            np += npospart[b * NB1 + i];
        }
        cs = wred(cs); rs = wred(rs); np = wred(np);
        const int lane = threadIdx.x & 63, wid = threadIdx.x >> 6;
        __syncthreads();                 // protect sred reuse across iterations
        if (lane == 0) { sred[wid] = cs; sred[4 + wid] = rs; sred[8 + wid] = np; }
        __syncthreads();
        if (threadIdx.x == 0) {
            const float csT = sred[0] + sred[1] + sred[2] + sred[3];
            const float rsT = sred[4] + sred[5] + sred[6] + sred[7];
            const float npT = sred[8] + sred[9] + sred[10] + sred[11];
            const float fnp = fmaxf(npT, 1.0f);
            clsAcc += csT / fnp;
            regAcc += rsT / (4.0f * fnp);
        }
    }
    if (threadIdx.x == 0) {
        const float cl = clsAcc / (float)B_N;
        const float rl = regAcc / (float)B_N;
        out[0] = cl;
        out[1] = rl;
        out[2] = cl + rl;
    }
}

extern "C" void kernel_launch(void* const* d_in, const int* in_sizes, int n_in,
                              void* d_out, int out_size, void* d_ws, size_t ws_size,
                              hipStream_t stream) {
    const float* cls_logits = (const float*)d_in[0];  // (B,A,K)
    const float* reg_preds  = (const float*)d_in[1];  // (B,A,4)
    const float* anchors    = (const float*)d_in[2];  // (A,4)
    const float* boxes      = (const float*)d_in[3];  // (B,M,4)
    const int*   classes    = (const int*)d_in[4];    // (B,M)
    float* out = (float*)d_out;

    char* ws = (char*)d_ws;
    int*   status   = (int*)ws;   ws += (size_t)B_N * A_N * sizeof(int);    // 1.57 MB
    float* clspart  = (float*)ws; ws += (size_t)B_N * NC2 * sizeof(float);  // 123 KB
    float* regpart  = (float*)ws; ws += (size_t)B_N * NB1 * sizeof(float);  // 6 KB
    float* npospart = (float*)ws;                                           // 6 KB

    dim3 g1(NB1, B_N);
    assign_kernel<<<g1, 256, 0, stream>>>(anchors, reg_preds, boxes, classes,
                                          status, regpart, npospart);
    dim3 g2(NC2, B_N);
    focal_kernel<<<g2, 256, 0, stream>>>(cls_logits, status, clspart);
    finalize_kernel<<<1, 256, 0, stream>>>(clspart, regpart, npospart, out);
}

// Round 4
// 236.137 us; speedup vs baseline: 1.0044x; 1.0044x over previous
//
#include <hip/hip_runtime.h>
#include <math.h>

// Problem constants (match reference)
#define B_N 8
#define A_N 49104
#define M_N 50
#define K_N 80
#define BETA_C (1.0f / 9.0f)

#define NB1 192                  // ceil(A_N/256) blocks per image for assign
#define NQ  (A_N * K_N / 4)      // 982080 float4 elements per image
#define NC2 3837                 // ceil(NQ/256) blocks per image for focal

__device__ __forceinline__ float wred(float v) {
#pragma unroll
    for (int off = 32; off > 0; off >>= 1) v += __shfl_down(v, off, 64);
    return v;
}

// Kernel 1: per-anchor box assignment + regression loss partials.
// grid = (NB1, B_N), block = 256
__global__ __launch_bounds__(256) void assign_kernel(
    const float* __restrict__ anchors,   // (A,4)
    const float* __restrict__ reg,       // (B,A,4)
    const float* __restrict__ boxes,     // (B,M,4), -1 padded
    const int* __restrict__ classes,     // (B,M)
    int* __restrict__ status,            // (B,A): -1 ignore, 0 neg, c>=1 pos class
    float* __restrict__ regpart,         // (B,NB1)
    float* __restrict__ npospart)        // (B,NB1)
{
    const int b = blockIdx.y;
    const int a = blockIdx.x * 256 + threadIdx.x;

    __shared__ float sb[M_N * 4];
    __shared__ int   sc[M_N];
    if (threadIdx.x < M_N * 4) sb[threadIdx.x] = boxes[b * M_N * 4 + threadIdx.x];
    if (threadIdx.x < M_N)     sc[threadIdx.x] = classes[b * M_N + threadIdx.x];
    __syncthreads();

    float regl = 0.0f;
    float posf = 0.0f;

    if (a < A_N) {
        const float4 an = ((const float4*)anchors)[a];
        const float aw = an.z - an.x;
        const float ah = an.w - an.y;
        const float areaA = aw * ah;

        float best = -2.0f;
        int bi = 0;
#pragma unroll 5
        for (int m = 0; m < M_N; ++m) {
            const float bx0 = sb[4 * m + 0];
            const float by0 = sb[4 * m + 1];
            const float bx1 = sb[4 * m + 2];
            const float by1 = sb[4 * m + 3];
            float val = -1.0f;           // masked (invalid) boxes -> -1.0 exactly
            if (bx0 != -1.0f) {
                const float iw = fmaxf(fminf(an.z, bx1) - fmaxf(an.x, bx0), 0.0f);
                const float ih = fmaxf(fminf(an.w, by1) - fmaxf(an.y, by0), 0.0f);
                const float inter = iw * ih;
                const float ua = fmaxf(areaA + (bx1 - bx0) * (by1 - by0) - inter, 1e-8f);
                val = inter / ua;
            }
            if (val > best) { best = val; bi = m; }  // strict > == first argmax
        }

        int s;
        if (best >= 0.5f) {
            s = sc[bi];
            posf = 1.0f;
            // regression loss for positive anchor (precise logf here: only ~npos evals)
            const float4 r = ((const float4*)reg)[b * A_N + a];
            const float gx0 = sb[4 * bi + 0], gy0 = sb[4 * bi + 1];
            const float gx1 = sb[4 * bi + 2], gy1 = sb[4 * bi + 3];
            const float acx = an.x + 0.5f * aw;
            const float acy = an.y + 0.5f * ah;
            const float gw0 = gx1 - gx0;
            const float gh0 = gy1 - gy0;
            const float gcx = gx0 + 0.5f * gw0;
            const float gcy = gy0 + 0.5f * gh0;
            const float gw = fmaxf(gw0, 1.0f);
            const float gh = fmaxf(gh0, 1.0f);
            const float t0 = ((gcx - acx) / aw) / 0.1f;
            const float t1 = ((gcy - acy) / ah) / 0.1f;
            const float t2 = logf(gw / aw) / 0.2f;
            const float t3 = logf(gh / ah) / 0.2f;
            float d, sl;
            d = fabsf(t0 - r.x); sl  = (d <= BETA_C) ? 0.5f * d * d / BETA_C : d - 0.5f * BETA_C;
            d = fabsf(t1 - r.y); sl += (d <= BETA_C) ? 0.5f * d * d / BETA_C : d - 0.5f * BETA_C;
            d = fabsf(t2 - r.z); sl += (d <= BETA_C) ? 0.5f * d * d / BETA_C : d - 0.5f * BETA_C;
            d = fabsf(t3 - r.w); sl += (d <= BETA_C) ? 0.5f * d * d / BETA_C : d - 0.5f * BETA_C;
            regl = sl;
        } else {
            s = (best < 0.4f) ? 0 : -1;
        }
        status[b * A_N + a] = s;
    }

    // block reduce (regl, posf)
    const float rw = wred(regl);
    const float pw = wred(posf);
    __shared__ float sred[8];
    const int lane = threadIdx.x & 63, wid = threadIdx.x >> 6;
    if (lane == 0) { sred[wid] = rw; sred[4 + wid] = pw; }
    __syncthreads();
    if (threadIdx.x == 0) {
        regpart[b * NB1 + blockIdx.x]  = sred[0] + sred[1] + sred[2] + sred[3];
        npospart[b * NB1 + blockIdx.x] = sred[4] + sred[5] + sred[6] + sred[7];
    }
}

// Kernel 2: focal loss over all (a,k) elements. One float4 per thread.
// Deltas vs R1: load skipped for ignored anchors (exonerated in R3),
// and __logf (v_log_f32) instead of precise logf — THE R4 bisection variable.
// grid = (NC2, B_N), block = 256
__global__ __launch_bounds__(256) void focal_kernel(
    const float* __restrict__ logits,    // (B, A*K)
    const int* __restrict__ status,      // (B, A)
    float* __restrict__ clspart)         // (B, NC2)
{
    const int b = blockIdx.y;
    const int i4 = blockIdx.x * 256 + threadIdx.x;

    float sum = 0.0f;
    if (i4 < NQ) {
        const int e = i4 * 4;            // element index within image
        const int a = e / K_N;           // K=80, float4 never crosses a row
        const int k0 = e - a * K_N;
        const int s = status[b * A_N + a];
        if (s >= 0) {                    // not ignored: load + accumulate
            const float4 p4 = ((const float4*)(logits + (size_t)b * (A_N * (size_t)K_N)))[i4];
            const float pv[4] = {p4.x, p4.y, p4.z, p4.w};
#pragma unroll
            for (int j = 0; j < 4; ++j) {
                float p = fminf(fmaxf(pv[j], 1e-4f), 1.0f - 1e-4f);
                const bool ispos = (s >= 1) && (k0 + j == s - 1);
                // pos: 0.25*(1-p)^2*(-log p); neg: 0.75*p^2*(-log(1-p))
                const float la = ispos ? p : (1.0f - p);   // log argument
                const float fw = 1.0f - la;                 // focal weight
                const float alpha = ispos ? 0.25f : 0.75f;
                sum += alpha * fw * fw * (-__logf(la));
            }
        }
    }

    const float w = wred(sum);
    __shared__ float sred[4];
    const int lane = threadIdx.x & 63, wid = threadIdx.x >> 6;
    if (lane == 0) sred[wid] = w;
    __syncthreads();
    if (threadIdx.x == 0)
        clspart[b * NC2 + blockIdx.x] = sred[0] + sred[1] + sred[2] + sred[3];
}

// Kernel 3: final reduction + normalization. 1 block, 256 threads.
__global__ __launch_bounds__(256) void finalize_kernel(
    const float* __restrict__ clspart,
    const float* __restrict__ regpart,
    const float* __restrict__ npospart,
    float* __restrict__ out)
{
    __shared__ float sred[12];
    float clsAcc = 0.0f, regAcc = 0.0f;  // meaningful on thread 0 only

    for (int b = 0; b < B_N; ++b) {
        float cs = 0.0f, rs = 0.0f, np = 0.0f;
        for (int i = threadIdx.x; i < NC2; i += 256) cs += clspart[b * NC2 + i];
        for (int i = threadIdx.x; i < NB1; i += 256) {
            rs += regpart[b * NB1 + i];
            np += npospart[b * NB1 + i];
        }
        cs = wred(cs); rs = wred(rs); np = wred(np);
        const int lane = threadIdx.x & 63, wid = threadIdx.x >> 6;
        __syncthreads();                 // protect sred reuse across iterations
        if (lane == 0) { sred[wid] = cs; sred[4 + wid] = rs; sred[8 + wid] = np; }
        __syncthreads();
        if (threadIdx.x == 0) {
            const float csT = sred[0] + sred[1] + sred[2] + sred[3];
            const float rsT = sred[4] + sred[5] + sred[6] + sred[7];
            const float npT = sred[8] + sred[9] + sred[10] + sred[11];
            const float fnp = fmaxf(npT, 1.0f);
            clsAcc += csT / fnp;
            regAcc += rsT / (4.0f * fnp);
        }
    }
    if (threadIdx.x == 0) {
        const float cl = clsAcc / (float)B_N;
        const float rl = regAcc / (float)B_N;
        out[0] = cl;
        out[1] = rl;
        out[2] = cl + rl;
    }
}

extern "C" void kernel_launch(void* const* d_in, const int* in_sizes, int n_in,
                              void* d_out, int out_size, void* d_ws, size_t ws_size,
                              hipStream_t stream) {
    const float* cls_logits = (const float*)d_in[0];  // (B,A,K)
    const float* reg_preds  = (const float*)d_in[1];  // (B,A,4)
    const float* anchors    = (const float*)d_in[2];  // (A,4)
    const float* boxes      = (const float*)d_in[3];  // (B,M,4)
    const int*   classes    = (const int*)d_in[4];    // (B,M)
    float* out = (float*)d_out;

    char* ws = (char*)d_ws;
    int*   status   = (int*)ws;   ws += (size_t)B_N * A_N * sizeof(int);    // 1.57 MB
    float* clspart  = (float*)ws; ws += (size_t)B_N * NC2 * sizeof(float);  // 123 KB
    float* regpart  = (float*)ws; ws += (size_t)B_N * NB1 * sizeof(float);  // 6 KB
    float* npospart = (float*)ws;                                           // 6 KB

    dim3 g1(NB1, B_N);
    assign_kernel<<<g1, 256, 0, stream>>>(anchors, reg_preds, boxes, classes,
                                          status, regpart, npospart);
    dim3 g2(NC2, B_N);
    focal_kernel<<<g2, 256, 0, stream>>>(cls_logits, status, clspart);
    finalize_kernel<<<1, 256, 0, stream>>>(clspart, regpart, npospart, out);
}

// Round 5
// 208.695 us; speedup vs baseline: 1.1365x; 1.1315x over previous
//
#include <hip/hip_runtime.h>
#include <math.h>

// Problem constants (match reference)
#define B_N 8
#define A_N 49104
#define M_N 50
#define K_N 80
#define BETA_C (1.0f / 9.0f)

#define APB  256                 // anchors per block
#define NBLK 192                 // ceil(A_N/APB)
#define F4PA 20                  // float4 per anchor (K=80 / 4)

__device__ __forceinline__ float wred(float v) {
#pragma unroll
    for (int off = 32; off > 0; off >>= 1) v += __shfl_down(v, off, 64);
    return v;
}

// Fused kernel: phase 1 = per-anchor assignment + reg loss (256 anchors/block,
// status kept in LDS); phase 2 = focal loss over those anchors' logits.
// Components individually verified: load-skip (R3), __logf (R4).
// grid = (NBLK, B_N), block = 256
__global__ __launch_bounds__(256) void fused_kernel(
    const float* __restrict__ logits,    // (B, A*K)
    const float* __restrict__ reg,       // (B,A,4)
    const float* __restrict__ anchors,   // (A,4)
    const float* __restrict__ boxes,     // (B,M,4), -1 padded
    const int* __restrict__ classes,     // (B,M)
    float* __restrict__ clspart,         // (B,NBLK)
    float* __restrict__ regpart,         // (B,NBLK)
    float* __restrict__ npospart)        // (B,NBLK)
{
    const int b   = blockIdx.y;
    const int a0  = blockIdx.x * APB;
    const int tid = threadIdx.x;
    const int a   = a0 + tid;

    __shared__ float sb[M_N * 4];
    __shared__ int   sc[M_N];
    __shared__ int   sstat[APB];
    if (tid < M_N * 4) sb[tid] = boxes[b * M_N * 4 + tid];
    if (tid < M_N)     sc[tid] = classes[b * M_N + tid];
    __syncthreads();

    // ---------------- phase 1: assignment + smooth-L1 ----------------
    float regl = 0.0f;
    float posf = 0.0f;
    int s = -1;                          // out-of-range anchors -> ignored

    if (a < A_N) {
        const float4 an = ((const float4*)anchors)[a];
        const float aw = an.z - an.x;
        const float ah = an.w - an.y;
        const float areaA = aw * ah;

        float best = -2.0f;
        int bi = 0;
#pragma unroll 5
        for (int m = 0; m < M_N; ++m) {
            const float bx0 = sb[4 * m + 0];
            const float by0 = sb[4 * m + 1];
            const float bx1 = sb[4 * m + 2];
            const float by1 = sb[4 * m + 3];
            float val = -1.0f;           // masked (invalid) boxes -> -1.0 exactly
            if (bx0 != -1.0f) {
                const float iw = fmaxf(fminf(an.z, bx1) - fmaxf(an.x, bx0), 0.0f);
                const float ih = fmaxf(fminf(an.w, by1) - fmaxf(an.y, by0), 0.0f);
                const float inter = iw * ih;
                const float ua = fmaxf(areaA + (bx1 - bx0) * (by1 - by0) - inter, 1e-8f);
                val = inter / ua;
            }
            if (val > best) { best = val; bi = m; }  // strict > == first argmax
        }

        if (best >= 0.5f) {
            s = sc[bi];
            posf = 1.0f;
            const float4 r = ((const float4*)reg)[b * A_N + a];
            const float gx0 = sb[4 * bi + 0], gy0 = sb[4 * bi + 1];
            const float gx1 = sb[4 * bi + 2], gy1 = sb[4 * bi + 3];
            const float acx = an.x + 0.5f * aw;
            const float acy = an.y + 0.5f * ah;
            const float gw0 = gx1 - gx0;
            const float gh0 = gy1 - gy0;
            const float gcx = gx0 + 0.5f * gw0;
            const float gcy = gy0 + 0.5f * gh0;
            const float gw = fmaxf(gw0, 1.0f);
            const float gh = fmaxf(gh0, 1.0f);
            const float t0 = ((gcx - acx) / aw) / 0.1f;
            const float t1 = ((gcy - acy) / ah) / 0.1f;
            const float t2 = logf(gw / aw) / 0.2f;
            const float t3 = logf(gh / ah) / 0.2f;
            float d, sl;
            d = fabsf(t0 - r.x); sl  = (d <= BETA_C) ? 0.5f * d * d / BETA_C : d - 0.5f * BETA_C;
            d = fabsf(t1 - r.y); sl += (d <= BETA_C) ? 0.5f * d * d / BETA_C : d - 0.5f * BETA_C;
            d = fabsf(t2 - r.z); sl += (d <= BETA_C) ? 0.5f * d * d / BETA_C : d - 0.5f * BETA_C;
            d = fabsf(t3 - r.w); sl += (d <= BETA_C) ? 0.5f * d * d / BETA_C : d - 0.5f * BETA_C;
            regl = sl;
        } else if (best < 0.4f) {
            s = 0;
        }
    }
    sstat[tid] = s;
    __syncthreads();

    // ---------------- phase 2: focal loss for this block's anchors ----------------
    const float4* img4 = (const float4*)(logits + (size_t)b * ((size_t)A_N * K_N));
    float cls = 0.0f;
#pragma unroll 5
    for (int it = 0; it < F4PA; ++it) {
        const int li = it * APB + tid;        // 0..5119 local float4 index
        const int la = li / F4PA;             // local anchor 0..255
        const int k0 = (li - la * F4PA) * 4;  // class offset of this float4
        const int st = sstat[la];
        if (st >= 0) {                        // skip ignored: avoids the load entirely
            const float4 p4 = img4[(size_t)a0 * F4PA + li];
            const float pv[4] = {p4.x, p4.y, p4.z, p4.w};
#pragma unroll
            for (int j = 0; j < 4; ++j) {
                const float p = fminf(fmaxf(pv[j], 1e-4f), 1.0f - 1e-4f);
                const bool ispos = (st >= 1) && (k0 + j == st - 1);
                // pos: 0.25*(1-p)^2*(-log p); neg: 0.75*p^2*(-log(1-p))
                const float larg  = ispos ? p : (1.0f - p);
                const float fw    = 1.0f - larg;
                const float alpha = ispos ? 0.25f : 0.75f;
                cls += alpha * fw * fw * (-__logf(larg));
            }
        }
    }

    // ---------------- block reduction ----------------
    const float cw = wred(cls);
    const float rw = wred(regl);
    const float pw = wred(posf);
    __shared__ float sred[12];
    const int lane = tid & 63, wid = tid >> 6;
    if (lane == 0) { sred[wid] = cw; sred[4 + wid] = rw; sred[8 + wid] = pw; }
    __syncthreads();
    if (tid == 0) {
        clspart[b * NBLK + blockIdx.x]  = sred[0] + sred[1] + sred[2] + sred[3];
        regpart[b * NBLK + blockIdx.x]  = sred[4] + sred[5] + sred[6] + sred[7];
        npospart[b * NBLK + blockIdx.x] = sred[8] + sred[9] + sred[10] + sred[11];
    }
}

// Final reduction + normalization. 1 block, 256 threads. Deterministic.
__global__ __launch_bounds__(256) void finalize_kernel(
    const float* __restrict__ clspart,
    const float* __restrict__ regpart,
    const float* __restrict__ npospart,
    float* __restrict__ out)
{
    __shared__ float sred[12];
    float clsAcc = 0.0f, regAcc = 0.0f;  // meaningful on thread 0 only

    for (int b = 0; b < B_N; ++b) {
        float cs = 0.0f, rs = 0.0f, np = 0.0f;
        for (int i = threadIdx.x; i < NBLK; i += 256) {
            cs += clspart[b * NBLK + i];
            rs += regpart[b * NBLK + i];
            np += npospart[b * NBLK + i];
        }
        cs = wred(cs); rs = wred(rs); np = wred(np);
        const int lane = threadIdx.x & 63, wid = threadIdx.x >> 6;
        __syncthreads();                 // protect sred reuse across iterations
        if (lane == 0) { sred[wid] = cs; sred[4 + wid] = rs; sred[8 + wid] = np; }
        __syncthreads();
        if (threadIdx.x == 0) {
            const float csT = sred[0] + sred[1] + sred[2] + sred[3];
            const float rsT = sred[4] + sred[5] + sred[6] + sred[7];
            const float npT = sred[8] + sred[9] + sred[10] + sred[11];
            const float fnp = fmaxf(npT, 1.0f);
            clsAcc += csT / fnp;
            regAcc += rsT / (4.0f * fnp);
        }
    }
    if (threadIdx.x == 0) {
        const float cl = clsAcc / (float)B_N;
        const float rl = regAcc / (float)B_N;
        out[0] = cl;
        out[1] = rl;
        out[2] = cl + rl;
    }
}

extern "C" void kernel_launch(void* const* d_in, const int* in_sizes, int n_in,
                              void* d_out, int out_size, void* d_ws, size_t ws_size,
                              hipStream_t stream) {
    const float* cls_logits = (const float*)d_in[0];  // (B,A,K)
    const float* reg_preds  = (const float*)d_in[1];  // (B,A,4)
    const float* anchors    = (const float*)d_in[2];  // (A,4)
    const float* boxes      = (const float*)d_in[3];  // (B,M,4)
    const int*   classes    = (const int*)d_in[4];    // (B,M)
    float* out = (float*)d_out;

    char* ws = (char*)d_ws;
    float* clspart  = (float*)ws; ws += (size_t)B_N * NBLK * sizeof(float);  // 6 KB
    float* regpart  = (float*)ws; ws += (size_t)B_N * NBLK * sizeof(float);  // 6 KB
    float* npospart = (float*)ws;                                            // 6 KB

    dim3 g1(NBLK, B_N);
    fused_kernel<<<g1, 256, 0, stream>>>(cls_logits, reg_preds, anchors, boxes,
                                         classes, clspart, regpart, npospart);
    finalize_kernel<<<1, 256, 0, stream>>>(clspart, regpart, npospart, out);
}